// Round 3
// baseline (473.260 us; speedup 1.0000x reference)
//
#include <hip/hip_runtime.h>
#include <math.h>

#define TT 32
#define EPSF 1e-9f

constexpr int BLOCK = 256;
constexpr int GRID  = 2048;

// Quad-lane broadcast-xor via DPP quad_perm (pure VALU, no DS pipe).
// XOR1: [1,0,3,2] = 0xB1   XOR2: [2,3,0,1] = 0x4E
template <int CTRL>
__device__ __forceinline__ float dpp_xor(float x) {
    return __int_as_float(__builtin_amdgcn_update_dpp(
        0, __float_as_int(x), CTRL, 0xF, 0xF, true));
}
#define XOR1 0xB1
#define XOR2 0x4E

// Single fused kernel. Layout: 4 lanes per row; lane j owns chunks j and j+4
// (chunk = float4). Each preds load instruction covers 16 contiguous 64B
// segments -> every fetched byte is consumed by that instruction alone.
// ws layout: [0] double loss_acc, [1] double sw_acc, byte16: uint counter.
__global__ __launch_bounds__(BLOCK) void nll_fused(
    const float* __restrict__ preds,
    const int*   __restrict__ targets,
    const float* __restrict__ weight,
    const float* __restrict__ sample_weight,
    double*      __restrict__ ws,
    float*       __restrict__ out,
    int N)
{
    __shared__ float w_sh[TT];
    __shared__ float wcm_sh[TT];
    __shared__ double red_l[BLOCK / 64];
    __shared__ double red_s[BLOCK / 64];

    const int tid = threadIdx.x;

    if (tid < TT) w_sh[tid] = weight[tid];
    __syncthreads();
    if (tid < TT) {
        float s = 0.f;
        for (int t = 0; t <= tid; ++t) s += w_sh[t];
        wcm_sh[tid] = s / (float)(tid + 1);
    }
    __syncthreads();

    const int j     = tid & 3;      // lane within quad
    const int base0 = 4 * j;        // global idx of first elem of chunk j
    const int base1 = 16 + 4 * j;   // global idx of first elem of chunk j+4

    long long g = (long long)blockIdx.x * (BLOCK / 4) + (tid >> 2);
    const long long stride = (long long)gridDim.x * (BLOCK / 4);

    float acc_loss = 0.f;   // every lane accumulates (x4 duplicate, scaled later)
    float acc_sw   = 0.f;

    const float4* preds4   = (const float4*)preds;
    const int2*   targets2 = (const int2*)targets;

    for (long long row = g; row < (long long)N; row += stride) {
        float4 a = preds4[row * 8 + j];        // elems [4j, 4j+4)
        float4 b = preds4[row * 8 + 4 + j];    // elems [16+4j, 16+4j+4)
        int2 t2  = targets2[row];
        float sw = sample_weight[row];

        // row max
        float m = fmaxf(fmaxf(fmaxf(a.x, a.y), fmaxf(a.z, a.w)),
                        fmaxf(fmaxf(b.x, b.y), fmaxf(b.z, b.w)));
        m = fmaxf(m, dpp_xor<XOR1>(m));
        m = fmaxf(m, dpp_xor<XOR2>(m));

        float e0 = __expf(a.x - m), e1 = __expf(a.y - m);
        float e2 = __expf(a.z - m), e3 = __expf(a.w - m);
        float e4 = __expf(b.x - m), e5 = __expf(b.y - m);
        float e6 = __expf(b.z - m), e7 = __expf(b.w - m);

        // per-chunk prefix sums
        float s0 = e0, s1 = s0 + e1, s2 = s1 + e2, s3 = s2 + e3;
        float t0 = e4, t1 = t0 + e5, t2_ = t1 + e6, t3 = t2_ + e7;

        float z = s3 + t3;
        z += dpp_xor<XOR1>(z);
        z += dpp_xor<XOR2>(z);
        float inv = __builtin_amdgcn_rcpf(z);

        int d    = t2.x < 0 ? 0 : (t2.x > TT - 1 ? TT - 1 : t2.x);
        int idx0 = d - base0;
        int idx1 = d - base1;

        // pd_e = exp at global index d, if owned by this lane
        float pd_e = 0.f;
        pd_e = (idx0 == 0) ? e0 : pd_e;
        pd_e = (idx0 == 1) ? e1 : pd_e;
        pd_e = (idx0 == 2) ? e2 : pd_e;
        pd_e = (idx0 == 3) ? e3 : pd_e;
        pd_e = (idx1 == 0) ? e4 : pd_e;
        pd_e = (idx1 == 1) ? e5 : pd_e;
        pd_e = (idx1 == 2) ? e6 : pd_e;
        pd_e = (idx1 == 3) ? e7 : pd_e;

        // cdf_e = sum of this lane's elems with global index <= d
        float c0 = 0.f;
        c0 = (idx0 >= 0) ? s0 : c0;
        c0 = (idx0 >= 1) ? s1 : c0;
        c0 = (idx0 >= 2) ? s2 : c0;
        c0 = (idx0 >= 3) ? s3 : c0;
        float c1 = 0.f;
        c1 = (idx1 >= 0) ? t0 : c1;
        c1 = (idx1 >= 1) ? t1 : c1;
        c1 = (idx1 >= 2) ? t2_ : c1;
        c1 = (idx1 >= 3) ? t3 : c1;
        float cdf_e = c0 + c1;

        pd_e  += dpp_xor<XOR1>(pd_e);
        pd_e  += dpp_xor<XOR2>(pd_e);
        cdf_e += dpp_xor<XOR1>(cdf_e);
        cdf_e += dpp_xor<XOR2>(cdf_e);

        float p_d = pd_e * inv;
        float cdf = cdf_e * inv;
        float Sd  = fminf(fmaxf(1.0f - cdf, EPSF), 1.0f);

        bool ev    = (t2.y != 0);
        float parg = ev ? p_d : Sd;
        float wt   = ev ? w_sh[d] : wcm_sh[d];

        acc_loss = fmaf(-__logf(parg) * wt, sw, acc_loss);
        acc_sw  += sw;
    }

    // block reduction (all lanes duplicated x4; scale by 0.25)
    double dl = (double)acc_loss;
    double ds = (double)acc_sw;
    for (int mask = 1; mask < 64; mask <<= 1) {
        dl += __shfl_xor(dl, mask);
        ds += __shfl_xor(ds, mask);
    }
    dl *= 0.25;
    ds *= 0.25;

    const int lane = tid & 63;
    const int w    = tid >> 6;
    if (lane == 0) { red_l[w] = dl; red_s[w] = ds; }
    __syncthreads();

    if (tid == 0) {
        double L = 0.0, S = 0.0;
        for (int i = 0; i < BLOCK / 64; ++i) { L += red_l[i]; S += red_s[i]; }
        atomicAdd(&ws[0], L);
        atomicAdd(&ws[1], S);
        __threadfence();
        unsigned int* counter = (unsigned int*)((char*)ws + 16);
        unsigned int old = atomicAdd(counter, 1u);
        if (old == gridDim.x - 1) {
            // last block to finish: all atomics above are globally visible
            __threadfence();
            double Lt = atomicAdd(&ws[0], 0.0);
            double St = atomicAdd(&ws[1], 0.0);
            double denom = St > 1e-9 ? St : 1e-9;
            out[0] = (float)(Lt / denom);
        }
    }
}

extern "C" void kernel_launch(void* const* d_in, const int* in_sizes, int n_in,
                              void* d_out, int out_size, void* d_ws, size_t ws_size,
                              hipStream_t stream) {
    const float* preds         = (const float*)d_in[0];
    const int*   targets       = (const int*)d_in[1];
    const float* weight        = (const float*)d_in[2];
    const float* sample_weight = (const float*)d_in[3];
    float*       out           = (float*)d_out;
    double*      ws            = (double*)d_ws;

    const int N = in_sizes[3];   // sample_weight has N elements

    // zero the 32-byte accumulator block (ws is poisoned 0xAA before each call)
    hipMemsetAsync(d_ws, 0, 32, stream);

    nll_fused<<<GRID, BLOCK, 0, stream>>>(preds, targets, weight, sample_weight,
                                          ws, out, N);
}

// Round 4
// 381.076 us; speedup vs baseline: 1.2419x; 1.2419x over previous
//
#include <hip/hip_runtime.h>
#include <math.h>

#define TT 32
#define EPSF 1e-9f

constexpr int BLOCK = 256;
constexpr int GRID  = 2048;   // 8 blocks/CU -> full 32-wave residency

// Quad-lane broadcast-xor via DPP quad_perm (pure VALU, no DS pipe).
// XOR1: [1,0,3,2] = 0xB1   XOR2: [2,3,0,1] = 0x4E
template <int CTRL>
__device__ __forceinline__ float dpp_xor(float x) {
    return __int_as_float(__builtin_amdgcn_update_dpp(
        0, __float_as_int(x), CTRL, 0xF, 0xF, true));
}
#define XOR1 0xB1
#define XOR2 0x4E

// Full per-row pipeline for one quad: a = elems [4j,4j+4), b = elems [16+4j,...).
__device__ __forceinline__ void process_row(
    float4 a, float4 b, int2 t2, float sw,
    const float* __restrict__ w_sh, const float* __restrict__ wcm_sh,
    int base0, int base1,
    float& acc_loss, float& acc_sw)
{
    float m = fmaxf(fmaxf(fmaxf(a.x, a.y), fmaxf(a.z, a.w)),
                    fmaxf(fmaxf(b.x, b.y), fmaxf(b.z, b.w)));
    m = fmaxf(m, dpp_xor<XOR1>(m));
    m = fmaxf(m, dpp_xor<XOR2>(m));

    float e0 = __expf(a.x - m), e1 = __expf(a.y - m);
    float e2 = __expf(a.z - m), e3 = __expf(a.w - m);
    float e4 = __expf(b.x - m), e5 = __expf(b.y - m);
    float e6 = __expf(b.z - m), e7 = __expf(b.w - m);

    float s0 = e0, s1 = s0 + e1, s2 = s1 + e2, s3 = s2 + e3;
    float t0 = e4, t1 = t0 + e5, t2s = t1 + e6, t3 = t2s + e7;

    float z = s3 + t3;
    z += dpp_xor<XOR1>(z);
    z += dpp_xor<XOR2>(z);
    float inv = __builtin_amdgcn_rcpf(z);

    int d    = t2.x < 0 ? 0 : (t2.x > TT - 1 ? TT - 1 : t2.x);
    int idx0 = d - base0;
    int idx1 = d - base1;

    float pd_e = 0.f;
    pd_e = (idx0 == 0) ? e0 : pd_e;
    pd_e = (idx0 == 1) ? e1 : pd_e;
    pd_e = (idx0 == 2) ? e2 : pd_e;
    pd_e = (idx0 == 3) ? e3 : pd_e;
    pd_e = (idx1 == 0) ? e4 : pd_e;
    pd_e = (idx1 == 1) ? e5 : pd_e;
    pd_e = (idx1 == 2) ? e6 : pd_e;
    pd_e = (idx1 == 3) ? e7 : pd_e;

    float c0 = 0.f;
    c0 = (idx0 >= 0) ? s0 : c0;
    c0 = (idx0 >= 1) ? s1 : c0;
    c0 = (idx0 >= 2) ? s2 : c0;
    c0 = (idx0 >= 3) ? s3 : c0;
    float c1 = 0.f;
    c1 = (idx1 >= 0) ? t0 : c1;
    c1 = (idx1 >= 1) ? t1 : c1;
    c1 = (idx1 >= 2) ? t2s : c1;
    c1 = (idx1 >= 3) ? t3 : c1;
    float cdf_e = c0 + c1;

    pd_e  += dpp_xor<XOR1>(pd_e);
    pd_e  += dpp_xor<XOR2>(pd_e);
    cdf_e += dpp_xor<XOR1>(cdf_e);
    cdf_e += dpp_xor<XOR2>(cdf_e);

    float p_d = pd_e * inv;
    float Sd  = fminf(fmaxf(1.0f - cdf_e * inv, EPSF), 1.0f);

    bool  ev   = (t2.y != 0);
    float parg = ev ? p_d : Sd;
    float wt   = ev ? w_sh[d] : wcm_sh[d];

    acc_loss = fmaf(-__logf(parg) * wt, sw, acc_loss);
    acc_sw  += sw;
}

// Kernel 1: per-block partials (double2 per block). 4 lanes/row, lane j owns
// chunks j and j+4; 2 rows unrolled per iteration so 8 global loads are in
// flight before any vmcnt wait (MLP — R3 was latency-bound at VGPR=20).
__global__ __launch_bounds__(BLOCK) void nll_partial(
    const float* __restrict__ preds,
    const int*   __restrict__ targets,
    const float* __restrict__ weight,
    const float* __restrict__ sample_weight,
    double*      __restrict__ partials,
    int N)
{
    __shared__ float w_sh[TT];
    __shared__ float wcm_sh[TT];
    __shared__ double red_l[BLOCK / 64];
    __shared__ double red_s[BLOCK / 64];

    const int tid = threadIdx.x;

    if (tid < TT) w_sh[tid] = weight[tid];
    __syncthreads();
    if (tid < TT) {
        float s = 0.f;
        for (int t = 0; t <= tid; ++t) s += w_sh[t];
        wcm_sh[tid] = s / (float)(tid + 1);
    }
    __syncthreads();

    const int j     = tid & 3;
    const int base0 = 4 * j;
    const int base1 = 16 + 4 * j;

    const long long g  = (long long)blockIdx.x * (BLOCK / 4) + (tid >> 2);
    const long long qs = (long long)gridDim.x * (BLOCK / 4);

    float acc_loss = 0.f;
    float acc_sw   = 0.f;

    const float4* preds4   = (const float4*)preds;
    const int2*   targets2 = (const int2*)targets;

    long long row = g;
    // paired iterations: issue both rows' loads before either row's compute
    for (; row + qs < (long long)N; row += 2 * qs) {
        long long r1 = row + qs;
        float4 a0 = preds4[row * 8 + j];
        float4 b0 = preds4[row * 8 + 4 + j];
        float4 a1 = preds4[r1 * 8 + j];
        float4 b1 = preds4[r1 * 8 + 4 + j];
        int2 t20  = targets2[row];
        int2 t21  = targets2[r1];
        float sw0 = sample_weight[row];
        float sw1 = sample_weight[r1];

        process_row(a0, b0, t20, sw0, w_sh, wcm_sh, base0, base1, acc_loss, acc_sw);
        process_row(a1, b1, t21, sw1, w_sh, wcm_sh, base0, base1, acc_loss, acc_sw);
    }
    if (row < (long long)N) {
        float4 a0 = preds4[row * 8 + j];
        float4 b0 = preds4[row * 8 + 4 + j];
        int2 t20  = targets2[row];
        float sw0 = sample_weight[row];
        process_row(a0, b0, t20, sw0, w_sh, wcm_sh, base0, base1, acc_loss, acc_sw);
    }

    // block reduction (x4 lane duplication; scale by 0.25)
    double dl = (double)acc_loss;
    double ds = (double)acc_sw;
    for (int mask = 1; mask < 64; mask <<= 1) {
        dl += __shfl_xor(dl, mask);
        ds += __shfl_xor(ds, mask);
    }
    dl *= 0.25;
    ds *= 0.25;

    const int lane = tid & 63;
    const int w    = tid >> 6;
    if (lane == 0) { red_l[w] = dl; red_s[w] = ds; }
    __syncthreads();
    if (tid == 0) {
        double L = 0.0, S = 0.0;
        for (int i = 0; i < BLOCK / 64; ++i) { L += red_l[i]; S += red_s[i]; }
        partials[2 * (long long)blockIdx.x + 0] = L;
        partials[2 * (long long)blockIdx.x + 1] = S;
    }
}

// Kernel 2: reduce per-block partials, finalize scalar.
__global__ __launch_bounds__(256) void nll_final(
    const double* __restrict__ partials, int nblocks, float* __restrict__ out)
{
    const int tid = threadIdx.x;
    double sl = 0.0, ss = 0.0;
    for (int i = tid; i < nblocks; i += 256) {
        sl += partials[2 * i + 0];
        ss += partials[2 * i + 1];
    }
    for (int mask = 1; mask < 64; mask <<= 1) {
        sl += __shfl_xor(sl, mask);
        ss += __shfl_xor(ss, mask);
    }
    __shared__ double s_l[4], s_s[4];
    const int w = tid >> 6;
    if ((tid & 63) == 0) { s_l[w] = sl; s_s[w] = ss; }
    __syncthreads();
    if (tid == 0) {
        double L = 0.0, S = 0.0;
        for (int i = 0; i < 4; ++i) { L += s_l[i]; S += s_s[i]; }
        double denom = S > 1e-9 ? S : 1e-9;
        out[0] = (float)(L / denom);
    }
}

extern "C" void kernel_launch(void* const* d_in, const int* in_sizes, int n_in,
                              void* d_out, int out_size, void* d_ws, size_t ws_size,
                              hipStream_t stream) {
    const float* preds         = (const float*)d_in[0];
    const int*   targets       = (const int*)d_in[1];
    const float* weight        = (const float*)d_in[2];
    const float* sample_weight = (const float*)d_in[3];
    float*       out           = (float*)d_out;
    double*      partials      = (double*)d_ws;

    const int N = in_sizes[3];

    int grid = GRID;
    size_t need = (size_t)grid * 2 * sizeof(double);
    if (ws_size < need) {
        grid = (int)(ws_size / (2 * sizeof(double)));
        if (grid < 1) grid = 1;
    }

    nll_partial<<<grid, BLOCK, 0, stream>>>(preds, targets, weight, sample_weight, partials, N);
    nll_final<<<1, 256, 0, stream>>>(partials, grid, out);
}